// Round 1
// baseline (64.753 us; speedup 1.0000x reference)
//
#include <hip/hip_runtime.h>
#include <hip/hip_bf16.h>

typedef __attribute__((ext_vector_type(8))) short bf16x8;
typedef __attribute__((ext_vector_type(4))) float f32x4;
typedef __attribute__((ext_vector_type(4))) int i32x4;

// RNE round two fp32 -> packed bf16 pair (elem a = low half)
__device__ inline unsigned int pack_bf2(float a, float b) {
    unsigned int ua = __builtin_bit_cast(unsigned int, a);
    unsigned int ub = __builtin_bit_cast(unsigned int, b);
    ua = (ua + 0x7fffu + ((ua >> 16) & 1u)) >> 16;
    ub = (ub + 0x7fffu + ((ub >> 16) & 1u)) >> 16;
    return (ub << 16) | (ua & 0xffffu);
}

// ---------------------------------------------------------------------------
// Kernel 1: repack conv_w [K=768][N=256] fp32 -> bf16 in MFMA B-fragment order.
// Bpack frag index t = (nt*24 + ks)*64 + lane, 8 bf16 per t (one int4).
// Fragment semantics: B[k][n], k = ks*32 + (lane>>4)*8 + j, n = nt*16 + (lane&15).
// ---------------------------------------------------------------------------
__global__ void pack_w_kernel(const float* __restrict__ conv_w, i32x4* __restrict__ bpack) {
    int t = blockIdx.x * 256 + threadIdx.x;       // 0 .. 24575
    int lane = t & 63;
    int g = t >> 6;                                // nt*24 + ks
    int nt = g / 24, ks = g - nt * 24;
    int k0 = ks * 32 + ((lane >> 4) << 3);
    int n  = nt * 16 + (lane & 15);
    const float* src = conv_w + (size_t)k0 * 256 + n;
    float v[8];
#pragma unroll
    for (int j = 0; j < 8; ++j) v[j] = src[(size_t)j * 256];
    i32x4 o;
    o.x = pack_bf2(v[0], v[1]);
    o.y = pack_bf2(v[2], v[3]);
    o.z = pack_bf2(v[4], v[5]);
    o.w = pack_bf2(v[6], v[7]);
    bpack[t] = o;
}

// ---------------------------------------------------------------------------
// Kernel 2: conv stem as bf16 MFMA patch-GEMM, no LDS.
// M=16384 (m=(b*32+i)*32+j), K=768 (k=(ky*16+kx)*3+ci), N=256.
// Block: 32 rows x 256 cols, 4 waves; wave w owns cols w*64..w*64+63.
// A fragments built straight from global fp32 (each element read once/block).
// ---------------------------------------------------------------------------
__global__ __launch_bounds__(256) void conv_kernel(
    const float* __restrict__ images,
    const i32x4* __restrict__ bpack,
    const float* __restrict__ conv_b,
    float* __restrict__ feat) {
    const int tid  = threadIdx.x;
    const int lane = tid & 63;
    const int w    = tid >> 6;        // wave 0..3
    const int l15  = lane & 15;
    const int lg   = lane >> 4;       // 0..3
    const int m0   = blockIdx.x * 32;

    // per-lane A row base (element offset into images) for mt = 0,1
    long arow[2];
#pragma unroll
    for (int mt = 0; mt < 2; ++mt) {
        int m = m0 + mt * 16 + l15;
        int b = m >> 10, i = (m >> 5) & 31, j = m & 31;
        arow[mt] = (long)((b << 9) + (i << 4)) * 1536 + j * 48;
    }
    float bias[4];
#pragma unroll
    for (int nt = 0; nt < 4; ++nt) bias[nt] = conv_b[w * 64 + nt * 16 + l15];

    f32x4 acc[2][4] = {};

    for (int kt = 0; kt < 12; ++kt) {
        bf16x8 aF[2][2];
#pragma unroll
        for (int mt = 0; mt < 2; ++mt)
#pragma unroll
        for (int ks = 0; ks < 2; ++ks) {
            int kg = kt * 64 + ks * 32 + (lg << 3);   // multiple of 8, < 768
            int ky = (kg * 1366) >> 16;               // exact /48 for kg<768
            int kk = kg - ky * 48;
            const float* p = images + arow[mt] + (long)ky * 1536 + kk;
            f32x4 f0 = *(const f32x4*)(p);
            f32x4 f1 = *(const f32x4*)(p + 4);
            i32x4 u;
            u.x = pack_bf2(f0.x, f0.y);
            u.y = pack_bf2(f0.z, f0.w);
            u.z = pack_bf2(f1.x, f1.y);
            u.w = pack_bf2(f1.z, f1.w);
            aF[mt][ks] = __builtin_bit_cast(bf16x8, u);
        }
#pragma unroll
        for (int nt = 0; nt < 4; ++nt) {
#pragma unroll
            for (int ks = 0; ks < 2; ++ks) {
                int ksg = kt * 2 + ks;
                i32x4 bv = bpack[(size_t)((w * 4 + nt) * 24 + ksg) * 64 + lane];
                bf16x8 bF = __builtin_bit_cast(bf16x8, bv);
#pragma unroll
                for (int mt = 0; mt < 2; ++mt)
                    acc[mt][nt] = __builtin_amdgcn_mfma_f32_16x16x32_bf16(
                        aF[mt][ks], bF, acc[mt][nt], 0, 0, 0);
            }
        }
    }
    // epilogue: D[row][col], row = 4*lg + r within 16-tile, col = l15
#pragma unroll
    for (int mt = 0; mt < 2; ++mt)
#pragma unroll
    for (int nt = 0; nt < 4; ++nt)
#pragma unroll
    for (int r = 0; r < 4; ++r) {
        int m = m0 + mt * 16 + lg * 4 + r;
        int n = w * 64 + nt * 16 + l15;
        float v = acc[mt][nt][r] + bias[nt];
        feat[(size_t)m * 256 + n] = fmaxf(v, 0.f);
    }
}

// ---------------------------------------------------------------------------
// Kernel 3: RoI-align (7x7 bilinear, mean) + mask + dense.  1 block per (b,n).
// 512 threads: h = tid>>8 splits samples (gather) then channel-halves (dense).
// ---------------------------------------------------------------------------
__global__ __launch_bounds__(512) void roi_dense_kernel(
    const float* __restrict__ bboxes,
    const float* __restrict__ feat,
    const float* __restrict__ dense_w,
    const float* __restrict__ dense_b,
    float* __restrict__ out) {
    __shared__ int   offs[4][49];
    __shared__ float wts[4][49];
    __shared__ float part[512];
    __shared__ float objv[256];

    const int bn = blockIdx.x;         // b*16 + n
    const int b  = bn >> 4;
    const int tid = threadIdx.x;

    const float4 box = *(const float4*)(bboxes + (size_t)bn * 4); // ymin,xmin,ymax,xmax
    bool empty = (box.x == -1.f) & (box.y == -1.f) & (box.z == -1.f) & (box.w == -1.f);
    if (empty) {
        if (tid < 256) out[(size_t)bn * 256 + tid] = dense_b[tid];
        return;
    }

    if (tid < 49) {
        int sy = tid / 7, sx = tid - sy * 7;
        float py = (box.x + (box.z - box.x) * ((sy + 0.5f) * (1.0f / 7.0f))) * 32.f - 0.5f;
        float px = (box.y + (box.w - box.y) * ((sx + 0.5f) * (1.0f / 7.0f))) * 32.f - 0.5f;
        float y0f = floorf(py), x0f = floorf(px);
        float wy = py - y0f, wx = px - x0f;
        int y0 = min(max((int)y0f, 0), 31);
        int y1 = min(max((int)y0f + 1, 0), 31);
        int x0 = min(max((int)x0f, 0), 31);
        int x1 = min(max((int)x0f + 1, 0), 31);
        offs[0][tid] = (y0 * 32 + x0) * 256;
        offs[1][tid] = (y0 * 32 + x1) * 256;
        offs[2][tid] = (y1 * 32 + x0) * 256;
        offs[3][tid] = (y1 * 32 + x1) * 256;
        wts[0][tid] = (1.f - wy) * (1.f - wx);
        wts[1][tid] = (1.f - wy) * wx;
        wts[2][tid] = wy * (1.f - wx);
        wts[3][tid] = wy * wx;
    }
    __syncthreads();

    const int c = tid & 255, h = tid >> 8;
    const float* fb = feat + (size_t)b * (1024 * 256) + c;
    float accv = 0.f;
    for (int s = h; s < 49; s += 2) {
        accv += wts[0][s] * fb[offs[0][s]];
        accv += wts[1][s] * fb[offs[1][s]];
        accv += wts[2][s] * fb[offs[2][s]];
        accv += wts[3][s] * fb[offs[3][s]];
    }
    part[tid] = accv;
    __syncthreads();
    if (tid < 256) objv[tid] = (part[tid] + part[tid + 256]) * (1.f / 49.f);
    __syncthreads();

    const float* dwp = dense_w + (size_t)(h * 128) * 256 + c;
    float da = 0.f;
#pragma unroll 8
    for (int cc = 0; cc < 128; ++cc) da += objv[h * 128 + cc] * dwp[(size_t)cc * 256];
    part[tid] = da;
    __syncthreads();
    if (tid < 256) out[(size_t)bn * 256 + tid] = part[tid] + part[tid + 256] + dense_b[tid];
}

extern "C" void kernel_launch(void* const* d_in, const int* in_sizes, int n_in,
                              void* d_out, int out_size, void* d_ws, size_t ws_size,
                              hipStream_t stream) {
    const float* images  = (const float*)d_in[0];   // [16,512,512,3]
    const float* bboxes  = (const float*)d_in[1];   // [16,16,4]
    const float* conv_w  = (const float*)d_in[2];   // [16,16,3,256]
    const float* conv_b  = (const float*)d_in[3];   // [256]
    const float* dense_w = (const float*)d_in[4];   // [256,256]
    const float* dense_b = (const float*)d_in[5];   // [256]
    float* out = (float*)d_out;

    char* ws = (char*)d_ws;
    i32x4* bpack = (i32x4*)ws;                      // 384 KiB (bf16 B fragments)
    float* feat  = (float*)(ws + 512 * 1024);       // 16384*256 fp32 = 16 MiB

    pack_w_kernel<<<96, 256, 0, stream>>>(conv_w, bpack);
    conv_kernel<<<512, 256, 0, stream>>>(images, bpack, conv_b, feat);
    roi_dense_kernel<<<256, 512, 0, stream>>>(bboxes, feat, dense_w, dense_b, out);
}

// Round 2
// 47.502 us; speedup vs baseline: 1.3632x; 1.3632x over previous
//
#include <hip/hip_runtime.h>
#include <hip/hip_bf16.h>

typedef __attribute__((ext_vector_type(8))) short bf16x8;
typedef __attribute__((ext_vector_type(4))) float f32x4;
typedef __attribute__((ext_vector_type(4))) int i32x4;

// RNE round two fp32 -> packed bf16 pair (elem a = low half)
__device__ inline unsigned int pack_bf2(float a, float b) {
    unsigned int ua = __builtin_bit_cast(unsigned int, a);
    unsigned int ub = __builtin_bit_cast(unsigned int, b);
    ua = (ua + 0x7fffu + ((ua >> 16) & 1u)) >> 16;
    ub = (ub + 0x7fffu + ((ub >> 16) & 1u)) >> 16;
    return (ub << 16) | (ua & 0xffffu);
}

// ---------------------------------------------------------------------------
// Kernel 1: repack conv_w [K=768][N=256] fp32 -> bf16 in MFMA B-fragment order.
// Bpack frag index t = (nt*24 + ksg)*64 + lane, 8 bf16 per t (one int4).
// Fragment semantics: B[k][n], k = ksg*32 + (lane>>4)*8 + j, n = nt*16 + (lane&15).
// ---------------------------------------------------------------------------
__global__ void pack_w_kernel(const float* __restrict__ conv_w, i32x4* __restrict__ bpack) {
    int t = blockIdx.x * 256 + threadIdx.x;       // 0 .. 24575
    int lane = t & 63;
    int g = t >> 6;                                // nt*24 + ksg
    int nt = g / 24, ks = g - nt * 24;
    int k0 = ks * 32 + ((lane >> 4) << 3);
    int n  = nt * 16 + (lane & 15);
    const float* src = conv_w + (size_t)k0 * 256 + n;
    float v[8];
#pragma unroll
    for (int j = 0; j < 8; ++j) v[j] = src[(size_t)j * 256];
    i32x4 o;
    o.x = pack_bf2(v[0], v[1]);
    o.y = pack_bf2(v[2], v[3]);
    o.z = pack_bf2(v[4], v[5]);
    o.w = pack_bf2(v[6], v[7]);
    bpack[t] = o;
}

// ---------------------------------------------------------------------------
// Kernel 2: conv stem as bf16 MFMA patch-GEMM with LDS-staged A.
// M=16384 (m=(b*32+i)*32+j), K=768 (k=(ky*16+kx)*3+ci), N=256.
// Block: 32 patch-rows (one image strip) x 128 cols. Grid 1024 = 512 mblk x 2 nhalf.
// K-chunk = 96 (2 image rows): stage 2x1536 contiguous floats coalesced,
// pack bf16 in-register, ds_write; fragments via ds_read_b128. Double-buffered.
// ---------------------------------------------------------------------------
__global__ __launch_bounds__(256) void conv_kernel(
    const float* __restrict__ images,
    const i32x4* __restrict__ bpack,
    const float* __restrict__ conv_b,
    float* __restrict__ feat) {
    __shared__ short ldsA[2][32 * 104];           // padded row stride 104 (96 data)

    const int tid  = threadIdx.x;
    const int lane = tid & 63;
    const int w    = tid >> 6;        // wave 0..3
    const int l15  = lane & 15;
    const int lg   = lane >> 4;       // 0..3
    const int mblk  = blockIdx.x >> 1;
    const int nhalf = blockIdx.x & 1;
    const int b = mblk >> 5, i = mblk & 31;
    const int wrow = (w >> 1) << 4;   // 0 or 16 (wave's M half)
    const int wn   = w & 1;           // wave's N quarter within half

    // staging coords: 2 rows x 128 threads, 3 float4 passes (stride 512 floats)
    const int tr = tid >> 7, tc = tid & 127;
    const float* rowbase = images + (size_t)(b * 512 + i * 16 + tr) * 1536 + tc * 4;

    float bias[4];
#pragma unroll
    for (int nt = 0; nt < 4; ++nt)
        bias[nt] = conv_b[nhalf * 128 + wn * 64 + nt * 16 + l15];

    const i32x4* bp = bpack + (size_t)(nhalf * 8 + wn * 4) * 24 * 64 + lane;

    f32x4 acc[4] = {};
    f32x4 st[3];

    // prologue: load + stage chunk 0
#pragma unroll
    for (int p = 0; p < 3; ++p) st[p] = *(const f32x4*)(rowbase + p * 512);
#pragma unroll
    for (int p = 0; p < 3; ++p) {
        int fidx = tc + 128 * p;              // float4 index within image row
        int j = fidx / 12;                    // patch column
        int q = fidx - 12 * j;
        int idx = j * 104 + tr * 48 + q * 4;  // bf16 elem index in LDS row j
        int2 v;
        v.x = pack_bf2(st[p].x, st[p].y);
        v.y = pack_bf2(st[p].z, st[p].w);
        *(int2*)(&ldsA[0][idx]) = v;
    }

    for (int c = 0; c < 8; ++c) {
        if (c < 7) {
            const float* rb = rowbase + (size_t)(2 * (c + 1)) * 1536;
#pragma unroll
            for (int p = 0; p < 3; ++p) st[p] = *(const f32x4*)(rb + p * 512);
        }
        __syncthreads();
        const short* bufA = ldsA[c & 1];
#pragma unroll
        for (int s = 0; s < 3; ++s) {
            bf16x8 aF = *(const bf16x8*)(&bufA[(wrow + l15) * 104 + s * 32 + lg * 8]);
            int ksg = c * 3 + s;
#pragma unroll
            for (int nt = 0; nt < 4; ++nt) {
                i32x4 bv = bp[(size_t)(nt * 24 + ksg) * 64];
                acc[nt] = __builtin_amdgcn_mfma_f32_16x16x32_bf16(
                    aF, __builtin_bit_cast(bf16x8, bv), acc[nt], 0, 0, 0);
            }
        }
        if (c < 7) {
            short* dstA = ldsA[(c + 1) & 1];
#pragma unroll
            for (int p = 0; p < 3; ++p) {
                int fidx = tc + 128 * p;
                int j = fidx / 12;
                int q = fidx - 12 * j;
                int idx = j * 104 + tr * 48 + q * 4;
                int2 v;
                v.x = pack_bf2(st[p].x, st[p].y);
                v.y = pack_bf2(st[p].z, st[p].w);
                *(int2*)(&dstA[idx]) = v;
            }
        }
    }

    // epilogue: D row within 16-tile = 4*lg + r, col = l15
    const int m0 = mblk * 32 + wrow;
    const int ncol = nhalf * 128 + wn * 64;
#pragma unroll
    for (int nt = 0; nt < 4; ++nt)
#pragma unroll
    for (int r = 0; r < 4; ++r) {
        int m = m0 + lg * 4 + r;
        float v = acc[nt][r] + bias[nt];
        feat[(size_t)m * 256 + ncol + nt * 16 + l15] = fmaxf(v, 0.f);
    }
}

// ---------------------------------------------------------------------------
// Kernel 3: RoI-align (7x7 bilinear, mean) + mask + dense.  1 block per (b,n).
// 512 threads: h = tid>>8 splits samples (gather) then channel-halves (dense).
// ---------------------------------------------------------------------------
__global__ __launch_bounds__(512) void roi_dense_kernel(
    const float* __restrict__ bboxes,
    const float* __restrict__ feat,
    const float* __restrict__ dense_w,
    const float* __restrict__ dense_b,
    float* __restrict__ out) {
    __shared__ int   offs[4][49];
    __shared__ float wts[4][49];
    __shared__ float part[512];
    __shared__ float objv[256];

    const int bn = blockIdx.x;         // b*16 + n
    const int b  = bn >> 4;
    const int tid = threadIdx.x;

    const float4 box = *(const float4*)(bboxes + (size_t)bn * 4); // ymin,xmin,ymax,xmax
    bool empty = (box.x == -1.f) & (box.y == -1.f) & (box.z == -1.f) & (box.w == -1.f);
    if (empty) {
        if (tid < 256) out[(size_t)bn * 256 + tid] = dense_b[tid];
        return;
    }

    if (tid < 49) {
        int sy = tid / 7, sx = tid - sy * 7;
        float py = (box.x + (box.z - box.x) * ((sy + 0.5f) * (1.0f / 7.0f))) * 32.f - 0.5f;
        float px = (box.y + (box.w - box.y) * ((sx + 0.5f) * (1.0f / 7.0f))) * 32.f - 0.5f;
        float y0f = floorf(py), x0f = floorf(px);
        float wy = py - y0f, wx = px - x0f;
        int y0 = min(max((int)y0f, 0), 31);
        int y1 = min(max((int)y0f + 1, 0), 31);
        int x0 = min(max((int)x0f, 0), 31);
        int x1 = min(max((int)x0f + 1, 0), 31);
        offs[0][tid] = (y0 * 32 + x0) * 256;
        offs[1][tid] = (y0 * 32 + x1) * 256;
        offs[2][tid] = (y1 * 32 + x0) * 256;
        offs[3][tid] = (y1 * 32 + x1) * 256;
        wts[0][tid] = (1.f - wy) * (1.f - wx);
        wts[1][tid] = (1.f - wy) * wx;
        wts[2][tid] = wy * (1.f - wx);
        wts[3][tid] = wy * wx;
    }
    __syncthreads();

    const int c = tid & 255, h = tid >> 8;
    const float* fb = feat + (size_t)b * (1024 * 256) + c;
    float accv = 0.f;
    for (int s = h; s < 49; s += 2) {
        accv += wts[0][s] * fb[offs[0][s]];
        accv += wts[1][s] * fb[offs[1][s]];
        accv += wts[2][s] * fb[offs[2][s]];
        accv += wts[3][s] * fb[offs[3][s]];
    }
    part[tid] = accv;
    __syncthreads();
    if (tid < 256) objv[tid] = (part[tid] + part[tid + 256]) * (1.f / 49.f);
    __syncthreads();

    const float* dwp = dense_w + (size_t)(h * 128) * 256 + c;
    float da = 0.f;
#pragma unroll 8
    for (int cc = 0; cc < 128; ++cc) da += objv[h * 128 + cc] * dwp[(size_t)cc * 256];
    part[tid] = da;
    __syncthreads();
    if (tid < 256) out[(size_t)bn * 256 + tid] = part[tid] + part[tid + 256] + dense_b[tid];
}

extern "C" void kernel_launch(void* const* d_in, const int* in_sizes, int n_in,
                              void* d_out, int out_size, void* d_ws, size_t ws_size,
                              hipStream_t stream) {
    const float* images  = (const float*)d_in[0];   // [16,512,512,3]
    const float* bboxes  = (const float*)d_in[1];   // [16,16,4]
    const float* conv_w  = (const float*)d_in[2];   // [16,16,3,256]
    const float* conv_b  = (const float*)d_in[3];   // [256]
    const float* dense_w = (const float*)d_in[4];   // [256,256]
    const float* dense_b = (const float*)d_in[5];   // [256]
    float* out = (float*)d_out;

    char* ws = (char*)d_ws;
    i32x4* bpack = (i32x4*)ws;                      // 384 KiB (bf16 B fragments)
    float* feat  = (float*)(ws + 512 * 1024);       // 16384*256 fp32 = 16 MiB

    pack_w_kernel<<<96, 256, 0, stream>>>(conv_w, bpack);
    conv_kernel<<<1024, 256, 0, stream>>>(images, bpack, conv_b, feat);
    roi_dense_kernel<<<256, 512, 0, stream>>>(bboxes, feat, dense_w, dense_b, out);
}

// Round 3
// 39.053 us; speedup vs baseline: 1.6581x; 1.2164x over previous
//
#include <hip/hip_runtime.h>
#include <hip/hip_bf16.h>

typedef __attribute__((ext_vector_type(8))) short bf16x8;
typedef __attribute__((ext_vector_type(4))) float f32x4;
typedef __attribute__((ext_vector_type(4))) int i32x4;

// RNE round two fp32 -> packed bf16 pair (elem a = low half)
__device__ inline unsigned int pack_bf2(float a, float b) {
    unsigned int ua = __builtin_bit_cast(unsigned int, a);
    unsigned int ub = __builtin_bit_cast(unsigned int, b);
    ua = (ua + 0x7fffu + ((ua >> 16) & 1u)) >> 16;
    ub = (ub + 0x7fffu + ((ub >> 16) & 1u)) >> 16;
    return (ub << 16) | (ua & 0xffffu);
}

// ---------------------------------------------------------------------------
// Kernel 1: repack conv_w [K=768][N=256] fp32 -> bf16 in MFMA B-fragment order.
// Bpack frag index t = (nt*24 + ksg)*64 + lane, 8 bf16 per t (one int4).
// Fragment semantics: B[k][n], k = ksg*32 + (lane>>4)*8 + j, n = nt*16 + (lane&15).
// ---------------------------------------------------------------------------
__global__ void pack_w_kernel(const float* __restrict__ conv_w, i32x4* __restrict__ bpack) {
    int t = blockIdx.x * 256 + threadIdx.x;       // 0 .. 24575
    int lane = t & 63;
    int g = t >> 6;                                // nt*24 + ksg
    int nt = g / 24, ks = g - nt * 24;
    int k0 = ks * 32 + ((lane >> 4) << 3);
    int n  = nt * 16 + (lane & 15);
    const float* src = conv_w + (size_t)k0 * 256 + n;
    float v[8];
#pragma unroll
    for (int j = 0; j < 8; ++j) v[j] = src[(size_t)j * 256];
    i32x4 o;
    o.x = pack_bf2(v[0], v[1]);
    o.y = pack_bf2(v[2], v[3]);
    o.z = pack_bf2(v[4], v[5]);
    o.w = pack_bf2(v[6], v[7]);
    bpack[t] = o;
}

// ---------------------------------------------------------------------------
// Kernel 2: conv stem as bf16 MFMA patch-GEMM.
// M=16384 (m=(b*32+i)*32+j), K=768, N=256.
// Block: 512 threads = 8 waves. Wave w: M=64 x N=16 (nt = nhalf*8 + w).
// Block tile: M=64 (strips 2mi, 2mi+1) x N=128 (nhalf). Grid 512 = 2/CU.
// B fragments held in VGPRs (two 12-reg halves, loaded off critical path).
// A: K-chunk=192 (4 image rows/strip) staged coalesced into LDS, dbuf,
// global loads issued one chunk ahead. XCD swizzle pairs nhalf on one XCD.
// ---------------------------------------------------------------------------
__global__ __launch_bounds__(512, 4) void conv_kernel(
    const float* __restrict__ images,
    const i32x4* __restrict__ bpack,
    const float* __restrict__ conv_b,
    float* __restrict__ feat) {
    __shared__ short ldsA[2][64 * 200];   // [buf][patch 0..63][k 0..191, stride 200]

    const int tid  = threadIdx.x;
    const int lane = tid & 63;
    const int w    = tid >> 6;        // wave 0..7
    const int l15  = lane & 15;
    const int lg   = lane >> 4;       // 0..3

    // XCD swizzle: 512 = 8 XCDs x 64; consecutive work pairs land on one XCD
    const int work  = (blockIdx.x & 7) * 64 + (blockIdx.x >> 3);
    const int mi    = work >> 1;      // strip pair: strips 2mi, 2mi+1
    const int nhalf = work & 1;

    // staging coords: strip ss, row-in-chunk sr, 64 lanes x 6 float4 per row
    const int ss = tid >> 8;
    const int sr = (tid >> 6) & 3;
    const int tc = tid & 63;
    const int gstrip = 2 * mi + ss;
    const float* rowbase = images
        + (size_t)(((gstrip >> 5) << 9) + ((gstrip & 31) << 4) + sr) * 1536 + tc * 4;

    const float bias = conv_b[nhalf * 128 + w * 16 + l15];
    const i32x4* bp = bpack + (size_t)((nhalf * 8 + w) * 24) * 64 + lane;

    bf16x8 breg[12];
    f32x4 acc[4] = {};
    f32x4 st[6];

    // load B half 0 (ksg 0..11)
#pragma unroll
    for (int u = 0; u < 12; ++u)
        breg[u] = __builtin_bit_cast(bf16x8, bp[(size_t)u * 64]);

    // prologue: stage chunk 0, issue loads for chunk 1
#pragma unroll
    for (int p = 0; p < 6; ++p) st[p] = *(const f32x4*)(rowbase + p * 256);
#pragma unroll
    for (int p = 0; p < 6; ++p) {
        int fp = tc + 64 * p;                 // float4 index in row [0,384)
        int j = fp / 12, q = fp - 12 * j;
        int idx = (ss * 32 + j) * 200 + sr * 48 + q * 4;
        int2 v;
        v.x = pack_bf2(st[p].x, st[p].y);
        v.y = pack_bf2(st[p].z, st[p].w);
        *(int2*)(&ldsA[0][idx]) = v;
    }
#pragma unroll
    for (int p = 0; p < 6; ++p) st[p] = *(const f32x4*)(rowbase + 4 * 1536 + p * 256);

    for (int c = 0; c < 4; ++c) {
        __syncthreads();
        const short* bufA = &ldsA[c & 1][0];
        // compute chunk c: 6 k-steps x 4 m-tiles
#pragma unroll
        for (int s = 0; s < 6; ++s) {
            bf16x8 aF[4];
#pragma unroll
            for (int mt = 0; mt < 4; ++mt)
                aF[mt] = *(const bf16x8*)(&bufA[(mt * 16 + l15) * 200 + s * 32 + lg * 8]);
#pragma unroll
            for (int mt = 0; mt < 4; ++mt)
                acc[mt] = __builtin_amdgcn_mfma_f32_16x16x32_bf16(
                    aF[mt], breg[(c & 1) * 6 + s], acc[mt], 0, 0, 0);
        }
        if (c == 1) {
            // load B half 1 (ksg 12..23) — consumed from chunk 2 onward
#pragma unroll
            for (int u = 0; u < 12; ++u)
                breg[u] = __builtin_bit_cast(bf16x8, bp[(size_t)(12 + u) * 64]);
        }
        if (c < 3) {
            // write staged chunk c+1 into other buffer
            short* dstA = &ldsA[(c + 1) & 1][0];
#pragma unroll
            for (int p = 0; p < 6; ++p) {
                int fp = tc + 64 * p;
                int j = fp / 12, q = fp - 12 * j;
                int idx = (ss * 32 + j) * 200 + sr * 48 + q * 4;
                int2 v;
                v.x = pack_bf2(st[p].x, st[p].y);
                v.y = pack_bf2(st[p].z, st[p].w);
                *(int2*)(&dstA[idx]) = v;
            }
            if (c < 2) {
                // issue global loads for chunk c+2
                const float* rb = rowbase + (size_t)(4 * (c + 2)) * 1536;
#pragma unroll
                for (int p = 0; p < 6; ++p) st[p] = *(const f32x4*)(rb + p * 256);
            }
        }
    }

    // epilogue: D row in 16-tile = 4*lg + r, col = l15
    const int m0 = mi * 64;
    const int ncol = nhalf * 128 + w * 16 + l15;
#pragma unroll
    for (int mt = 0; mt < 4; ++mt)
#pragma unroll
    for (int r = 0; r < 4; ++r) {
        int m = m0 + mt * 16 + lg * 4 + r;
        float v = acc[mt][r] + bias;
        feat[(size_t)m * 256 + ncol] = fmaxf(v, 0.f);
    }
}

// ---------------------------------------------------------------------------
// Kernel 3: RoI-align (7x7 bilinear, mean) + mask + dense.  1 block per (b,n).
// 512 threads: h = tid>>8 splits samples (gather) then channel-halves (dense).
// ---------------------------------------------------------------------------
__global__ __launch_bounds__(512) void roi_dense_kernel(
    const float* __restrict__ bboxes,
    const float* __restrict__ feat,
    const float* __restrict__ dense_w,
    const float* __restrict__ dense_b,
    float* __restrict__ out) {
    __shared__ int   offs[4][49];
    __shared__ float wts[4][49];
    __shared__ float part[512];
    __shared__ float objv[256];

    const int bn = blockIdx.x;         // b*16 + n
    const int b  = bn >> 4;
    const int tid = threadIdx.x;

    const float4 box = *(const float4*)(bboxes + (size_t)bn * 4); // ymin,xmin,ymax,xmax
    bool empty = (box.x == -1.f) & (box.y == -1.f) & (box.z == -1.f) & (box.w == -1.f);
    if (empty) {
        if (tid < 256) out[(size_t)bn * 256 + tid] = dense_b[tid];
        return;
    }

    if (tid < 49) {
        int sy = tid / 7, sx = tid - sy * 7;
        float py = (box.x + (box.z - box.x) * ((sy + 0.5f) * (1.0f / 7.0f))) * 32.f - 0.5f;
        float px = (box.y + (box.w - box.y) * ((sx + 0.5f) * (1.0f / 7.0f))) * 32.f - 0.5f;
        float y0f = floorf(py), x0f = floorf(px);
        float wy = py - y0f, wx = px - x0f;
        int y0 = min(max((int)y0f, 0), 31);
        int y1 = min(max((int)y0f + 1, 0), 31);
        int x0 = min(max((int)x0f, 0), 31);
        int x1 = min(max((int)x0f + 1, 0), 31);
        offs[0][tid] = (y0 * 32 + x0) * 256;
        offs[1][tid] = (y0 * 32 + x1) * 256;
        offs[2][tid] = (y1 * 32 + x0) * 256;
        offs[3][tid] = (y1 * 32 + x1) * 256;
        wts[0][tid] = (1.f - wy) * (1.f - wx);
        wts[1][tid] = (1.f - wy) * wx;
        wts[2][tid] = wy * (1.f - wx);
        wts[3][tid] = wy * wx;
    }
    __syncthreads();

    const int c = tid & 255, h = tid >> 8;
    const float* fb = feat + (size_t)b * (1024 * 256) + c;
    float accv = 0.f;
    for (int s = h; s < 49; s += 2) {
        accv += wts[0][s] * fb[offs[0][s]];
        accv += wts[1][s] * fb[offs[1][s]];
        accv += wts[2][s] * fb[offs[2][s]];
        accv += wts[3][s] * fb[offs[3][s]];
    }
    part[tid] = accv;
    __syncthreads();
    if (tid < 256) objv[tid] = (part[tid] + part[tid + 256]) * (1.f / 49.f);
    __syncthreads();

    const float* dwp = dense_w + (size_t)(h * 128) * 256 + c;
    float da = 0.f;
#pragma unroll 8
    for (int cc = 0; cc < 128; ++cc) da += objv[h * 128 + cc] * dwp[(size_t)cc * 256];
    part[tid] = da;
    __syncthreads();
    if (tid < 256) out[(size_t)bn * 256 + tid] = part[tid] + part[tid + 256] + dense_b[tid];
}

extern "C" void kernel_launch(void* const* d_in, const int* in_sizes, int n_in,
                              void* d_out, int out_size, void* d_ws, size_t ws_size,
                              hipStream_t stream) {
    const float* images  = (const float*)d_in[0];   // [16,512,512,3]
    const float* bboxes  = (const float*)d_in[1];   // [16,16,4]
    const float* conv_w  = (const float*)d_in[2];   // [16,16,3,256]
    const float* conv_b  = (const float*)d_in[3];   // [256]
    const float* dense_w = (const float*)d_in[4];   // [256,256]
    const float* dense_b = (const float*)d_in[5];   // [256]
    float* out = (float*)d_out;

    char* ws = (char*)d_ws;
    i32x4* bpack = (i32x4*)ws;                      // 384 KiB (bf16 B fragments)
    float* feat  = (float*)(ws + 512 * 1024);       // 16384*256 fp32 = 16 MiB

    pack_w_kernel<<<96, 256, 0, stream>>>(conv_w, bpack);
    conv_kernel<<<512, 512, 0, stream>>>(images, bpack, conv_b, feat);
    roi_dense_kernel<<<256, 512, 0, stream>>>(bboxes, feat, dense_w, dense_b, out);
}

// Round 4
// 38.712 us; speedup vs baseline: 1.6727x; 1.0088x over previous
//
#include <hip/hip_runtime.h>
#include <hip/hip_bf16.h>

typedef __attribute__((ext_vector_type(8))) short bf16x8;
typedef __attribute__((ext_vector_type(4))) float f32x4;
typedef __attribute__((ext_vector_type(4))) int i32x4;

// RNE round two fp32 -> packed bf16 pair (elem a = low half)
__device__ inline unsigned int pack_bf2(float a, float b) {
    unsigned int ua = __builtin_bit_cast(unsigned int, a);
    unsigned int ub = __builtin_bit_cast(unsigned int, b);
    ua = (ua + 0x7fffu + ((ua >> 16) & 1u)) >> 16;
    ub = (ub + 0x7fffu + ((ub >> 16) & 1u)) >> 16;
    return (ub << 16) | (ua & 0xffffu);
}

// ---------------------------------------------------------------------------
// Kernel 1: repack conv_w [K=768][N=256] fp32 -> bf16 in MFMA B-fragment order.
// Bpack frag index t = (nt*24 + ksg)*64 + lane, 8 bf16 per t (one int4).
// Fragment semantics: B[k][n], k = ksg*32 + (lane>>4)*8 + j, n = nt*16 + (lane&15).
// ---------------------------------------------------------------------------
__global__ void pack_w_kernel(const float* __restrict__ conv_w, i32x4* __restrict__ bpack) {
    int t = blockIdx.x * 256 + threadIdx.x;       // 0 .. 24575
    int lane = t & 63;
    int g = t >> 6;                                // nt*24 + ksg
    int nt = g / 24, ks = g - nt * 24;
    int k0 = ks * 32 + ((lane >> 4) << 3);
    int n  = nt * 16 + (lane & 15);
    const float* src = conv_w + (size_t)k0 * 256 + n;
    float v[8];
#pragma unroll
    for (int j = 0; j < 8; ++j) v[j] = src[(size_t)j * 256];
    i32x4 o;
    o.x = pack_bf2(v[0], v[1]);
    o.y = pack_bf2(v[2], v[3]);
    o.z = pack_bf2(v[4], v[5]);
    o.w = pack_bf2(v[6], v[7]);
    bpack[t] = o;
}

// ---------------------------------------------------------------------------
// Kernel 2: conv stem as bf16 MFMA patch-GEMM.
// M=16384 (m=(b*32+i)*32+j), K=768, N=256.
// Block: 512 thr = 8 waves (2M x 4N). Block tile M=64 (strip pair) x N=128.
// Wave tile M=32 x N=32 (2 mt x 2 nt) -> A-frag:MFMA = 0.5.
// K-chunk=96 (2 rows/strip) staged to LDS as bf16 (stride 104, conflict-free),
// double-buffered; B frags double-buffered in regs (6+6 i32x4) from L2.
// Register budget ~100 < 128 cap (launch_bounds 512,4): no spills.
// Grid 512 = 2 blocks/CU; XCD swizzle pairs the two N-halves of a strip pair.
// ---------------------------------------------------------------------------
__global__ __launch_bounds__(512, 4) void conv_kernel(
    const float* __restrict__ images,
    const i32x4* __restrict__ bpack,
    const float* __restrict__ conv_b,
    float* __restrict__ feat) {
    __shared__ short ldsA[2][64 * 104];   // [buf][patch 0..63][k 0..95, stride 104]

    const int tid  = threadIdx.x;
    const int lane = tid & 63;
    const int w    = tid >> 6;        // wave 0..7
    const int l15  = lane & 15;
    const int lg   = lane >> 4;       // 0..3
    const int wr   = w >> 2;          // wave M-row 0..1
    const int wc   = w & 3;           // wave N-col 0..3

    // XCD swizzle: 512 blocks = 8 XCDs x 64 works; consecutive works share strips
    const int work  = (blockIdx.x & 7) * 64 + (blockIdx.x >> 3);
    const int mi    = work >> 1;      // strip pair index (M-block of 64)
    const int nhalf = work & 1;

    // staging coords: strip ss (0..1), row-in-chunk sr (0..1), col tc (0..127)
    const int ss = tid >> 8;
    const int sr = (tid >> 7) & 1;
    const int tc = tid & 127;
    const int gstrip = 2 * mi + ss;
    const float* rowbase = images
        + (size_t)(((gstrip >> 5) << 9) + ((gstrip & 31) << 4) + sr) * 1536 + tc * 4;

    // staging LDS indices (3 writes/thread), precomputed
    int widx[3];
#pragma unroll
    for (int p = 0; p < 3; ++p) {
        int fp = tc + (p << 7);               // float4 index in row [0,384)
        int j = (fp * 1366) >> 14;            // fp/12 exact for fp<384
        int q = fp - 12 * j;
        widx[p] = (ss * 32 + j) * 104 + sr * 48 + (q << 2);
    }

    float bias[2];
#pragma unroll
    for (int sub = 0; sub < 2; ++sub)
        bias[sub] = conv_b[nhalf * 128 + wc * 32 + sub * 16 + l15];

    // B fragment base: nt = nhalf*8 + wc*2 + sub, frag offset ((sub*24)+ksg)*64
    const i32x4* bp = bpack + (size_t)((nhalf * 8 + wc * 2) * 24) * 64 + lane;

    f32x4 acc[2][2] = {};
    i32x4 Bc[2][3], Bn[2][3];
    f32x4 st[3];

    // ---- prologue: stage chunk 0, load B chunk 0 ----
#pragma unroll
    for (int p = 0; p < 3; ++p) st[p] = *(const f32x4*)(rowbase + p * 512);
#pragma unroll
    for (int sub = 0; sub < 2; ++sub)
#pragma unroll
    for (int s = 0; s < 3; ++s)
        Bc[sub][s] = bp[(size_t)(sub * 24 + s) * 64];
#pragma unroll
    for (int p = 0; p < 3; ++p) {
        int2 v;
        v.x = pack_bf2(st[p].x, st[p].y);
        v.y = pack_bf2(st[p].z, st[p].w);
        *(int2*)(&ldsA[0][widx[p]]) = v;
    }
    __syncthreads();

#pragma unroll
    for (int c = 0; c < 8; ++c) {
        // issue next-chunk global loads first (T14: latency hides under MFMAs)
        if (c < 7) {
            const float* rb = rowbase + (size_t)(c + 1) * 3072;
#pragma unroll
            for (int p = 0; p < 3; ++p) st[p] = *(const f32x4*)(rb + p * 512);
#pragma unroll
            for (int sub = 0; sub < 2; ++sub)
#pragma unroll
            for (int s = 0; s < 3; ++s)
                Bn[sub][s] = bp[(size_t)(sub * 24 + (c + 1) * 3 + s) * 64];
        }
        // compute chunk c from LDS buf (c&1)
        const short* bufA = &ldsA[c & 1][0];
#pragma unroll
        for (int s = 0; s < 3; ++s) {
            bf16x8 aF0 = *(const bf16x8*)(&bufA[(wr * 32 + l15) * 104 + s * 32 + lg * 8]);
            bf16x8 aF1 = *(const bf16x8*)(&bufA[(wr * 32 + 16 + l15) * 104 + s * 32 + lg * 8]);
#pragma unroll
            for (int sub = 0; sub < 2; ++sub) {
                bf16x8 bF = __builtin_bit_cast(bf16x8, Bc[sub][s]);
                acc[0][sub] = __builtin_amdgcn_mfma_f32_16x16x32_bf16(aF0, bF, acc[0][sub], 0, 0, 0);
                acc[1][sub] = __builtin_amdgcn_mfma_f32_16x16x32_bf16(aF1, bF, acc[1][sub], 0, 0, 0);
            }
        }
        // stage chunk c+1 into other buffer
        if (c < 7) {
            short* dstA = &ldsA[(c + 1) & 1][0];
#pragma unroll
            for (int p = 0; p < 3; ++p) {
                int2 v;
                v.x = pack_bf2(st[p].x, st[p].y);
                v.y = pack_bf2(st[p].z, st[p].w);
                *(int2*)(&dstA[widx[p]]) = v;
            }
        }
        __syncthreads();
        if (c < 7) {
#pragma unroll
            for (int sub = 0; sub < 2; ++sub)
#pragma unroll
            for (int s = 0; s < 3; ++s)
                Bc[sub][s] = Bn[sub][s];
        }
    }

    // epilogue: D row in 16-tile = 4*lg + r, col = l15
    const int m0 = mi * 64 + wr * 32;
    const int nc0 = nhalf * 128 + wc * 32;
#pragma unroll
    for (int mt = 0; mt < 2; ++mt)
#pragma unroll
    for (int sub = 0; sub < 2; ++sub)
#pragma unroll
    for (int r = 0; r < 4; ++r) {
        int m = m0 + mt * 16 + lg * 4 + r;
        float v = acc[mt][sub][r] + bias[sub];
        feat[(size_t)m * 256 + nc0 + sub * 16 + l15] = fmaxf(v, 0.f);
    }
}

// ---------------------------------------------------------------------------
// Kernel 3: RoI-align (7x7 bilinear, mean) + mask + dense.  1 block per (b,n).
// 512 threads: h = tid>>8 splits samples (gather) then channel-halves (dense).
// ---------------------------------------------------------------------------
__global__ __launch_bounds__(512) void roi_dense_kernel(
    const float* __restrict__ bboxes,
    const float* __restrict__ feat,
    const float* __restrict__ dense_w,
    const float* __restrict__ dense_b,
    float* __restrict__ out) {
    __shared__ int   offs[4][49];
    __shared__ float wts[4][49];
    __shared__ float part[512];
    __shared__ float objv[256];

    const int bn = blockIdx.x;         // b*16 + n
    const int b  = bn >> 4;
    const int tid = threadIdx.x;

    const float4 box = *(const float4*)(bboxes + (size_t)bn * 4); // ymin,xmin,ymax,xmax
    bool empty = (box.x == -1.f) & (box.y == -1.f) & (box.z == -1.f) & (box.w == -1.f);
    if (empty) {
        if (tid < 256) out[(size_t)bn * 256 + tid] = dense_b[tid];
        return;
    }

    if (tid < 49) {
        int sy = tid / 7, sx = tid - sy * 7;
        float py = (box.x + (box.z - box.x) * ((sy + 0.5f) * (1.0f / 7.0f))) * 32.f - 0.5f;
        float px = (box.y + (box.w - box.y) * ((sx + 0.5f) * (1.0f / 7.0f))) * 32.f - 0.5f;
        float y0f = floorf(py), x0f = floorf(px);
        float wy = py - y0f, wx = px - x0f;
        int y0 = min(max((int)y0f, 0), 31);
        int y1 = min(max((int)y0f + 1, 0), 31);
        int x0 = min(max((int)x0f, 0), 31);
        int x1 = min(max((int)x0f + 1, 0), 31);
        offs[0][tid] = (y0 * 32 + x0) * 256;
        offs[1][tid] = (y0 * 32 + x1) * 256;
        offs[2][tid] = (y1 * 32 + x0) * 256;
        offs[3][tid] = (y1 * 32 + x1) * 256;
        wts[0][tid] = (1.f - wy) * (1.f - wx);
        wts[1][tid] = (1.f - wy) * wx;
        wts[2][tid] = wy * (1.f - wx);
        wts[3][tid] = wy * wx;
    }
    __syncthreads();

    const int c = tid & 255, h = tid >> 8;
    const float* fb = feat + (size_t)b * (1024 * 256) + c;
    float accv = 0.f;
    for (int s = h; s < 49; s += 2) {
        accv += wts[0][s] * fb[offs[0][s]];
        accv += wts[1][s] * fb[offs[1][s]];
        accv += wts[2][s] * fb[offs[2][s]];
        accv += wts[3][s] * fb[offs[3][s]];
    }
    part[tid] = accv;
    __syncthreads();
    if (tid < 256) objv[tid] = (part[tid] + part[tid + 256]) * (1.f / 49.f);
    __syncthreads();

    const float* dwp = dense_w + (size_t)(h * 128) * 256 + c;
    float da = 0.f;
#pragma unroll 8
    for (int cc = 0; cc < 128; ++cc) da += objv[h * 128 + cc] * dwp[(size_t)cc * 256];
    part[tid] = da;
    __syncthreads();
    if (tid < 256) out[(size_t)bn * 256 + tid] = part[tid] + part[tid + 256] + dense_b[tid];
}

extern "C" void kernel_launch(void* const* d_in, const int* in_sizes, int n_in,
                              void* d_out, int out_size, void* d_ws, size_t ws_size,
                              hipStream_t stream) {
    const float* images  = (const float*)d_in[0];   // [16,512,512,3]
    const float* bboxes  = (const float*)d_in[1];   // [16,16,4]
    const float* conv_w  = (const float*)d_in[2];   // [16,16,3,256]
    const float* conv_b  = (const float*)d_in[3];   // [256]
    const float* dense_w = (const float*)d_in[4];   // [256,256]
    const float* dense_b = (const float*)d_in[5];   // [256]
    float* out = (float*)d_out;

    char* ws = (char*)d_ws;
    i32x4* bpack = (i32x4*)ws;                      // 384 KiB (bf16 B fragments)
    float* feat  = (float*)(ws + 512 * 1024);       // 16384*256 fp32 = 16 MiB

    pack_w_kernel<<<96, 256, 0, stream>>>(conv_w, bpack);
    conv_kernel<<<512, 512, 0, stream>>>(images, bpack, conv_b, feat);
    roi_dense_kernel<<<256, 512, 0, stream>>>(bboxes, feat, dense_w, dense_b, out);
}